// Round 1
// baseline (667.569 us; speedup 1.0000x reference)
//
#include <hip/hip_runtime.h>
#include <hip/hip_bf16.h>
#include <cstdint>
#include <cstddef>

// Problem constants (fixed by setup_inputs)
#define NB   32
#define NPOS 3136      // 56*56
#define NC   384
#define NHD  8
#define DH   48
#define NAG  16
#define MROWS (NB*NPOS)   // 100352
#define CQK  768

static constexpr float kScale = 0.14433756729740643f;   // 48^-0.5
static constexpr float kInv196 = 1.0f / 196.0f;

typedef __bf16 bf16x8 __attribute__((ext_vector_type(8)));
typedef float  f32x4  __attribute__((ext_vector_type(4)));

// ---------------- fp32 -> bf16 convert (x4 vectorized) ----------------
__global__ __launch_bounds__(256) void cvt4_kernel(const float* __restrict__ src,
                                                   __hip_bfloat16* __restrict__ dst,
                                                   int n4) {
    int i = blockIdx.x * 256 + threadIdx.x;
    if (i >= n4) return;
    float4 v = ((const float4*)src)[i];
    union { ushort4 u; __hip_bfloat16 h[4]; } p;
    p.h[0] = __float2bfloat16(v.x);
    p.h[1] = __float2bfloat16(v.y);
    p.h[2] = __float2bfloat16(v.z);
    p.h[3] = __float2bfloat16(v.w);
    ((ushort4*)dst)[i] = p.u;
}

// ---------------- bf16 MFMA GEMM: C[M][Nn] = A[M][K] * B[Nn][K]^T (+bias) ----------------
// 128x128 tile, BK=32, 256 threads (4 waves, 2x2 of 64x64), chunk-XOR LDS swizzle.
template<bool HAS_BIAS, bool OUT_BF16>
__global__ __launch_bounds__(256) void gemm_kernel(
    const __hip_bfloat16* __restrict__ A,
    const __hip_bfloat16* __restrict__ Bw,
    const float* __restrict__ bias,
    void* __restrict__ Cout,
    int M, int Nn, int K)
{
    __shared__ unsigned char smem[16384];
    unsigned char* smA = smem;
    unsigned char* smB = smem + 8192;

    const int t    = threadIdx.x;
    const int m0   = blockIdx.x * 128;
    const int n0   = blockIdx.y * 128;
    const int lane = t & 63;
    const int wv   = t >> 6;
    const int wm   = (wv >> 1) * 64;
    const int wn   = (wv & 1) * 64;
    const int lr   = lane & 15;
    const int lg   = lane >> 4;

    // staging decomposition: 512 16B-chunks per tile, 2 per thread
    const int r0 = t >> 2;      // row 0..63
    const int c0 = t & 3;       // 16B chunk within 64B row
    const int sc = (c0 ^ (r0 & 3)) << 4;   // swizzled chunk byte offset

    f32x4 acc[4][4] = {};

    const int nk = K >> 5;
    for (int kt = 0; kt < nk; ++kt) {
        const int k0 = kt << 5;
        // global loads (issued before barrier to overlap latency)
        uint4 a0 = *(const uint4*)(A  + (size_t)(m0 + r0)      * K + k0 + c0 * 8);
        uint4 a1 = *(const uint4*)(A  + (size_t)(m0 + r0 + 64) * K + k0 + c0 * 8);
        uint4 b0 = *(const uint4*)(Bw + (size_t)(n0 + r0)      * K + k0 + c0 * 8);
        uint4 b1 = *(const uint4*)(Bw + (size_t)(n0 + r0 + 64) * K + k0 + c0 * 8);
        __syncthreads();   // previous tile fully consumed
        *(uint4*)(smA + r0 * 64        + sc) = a0;
        *(uint4*)(smA + (r0 + 64) * 64 + sc) = a1;   // (r0+64)&3 == r0&3
        *(uint4*)(smB + r0 * 64        + sc) = b0;
        *(uint4*)(smB + (r0 + 64) * 64 + sc) = b1;
        __syncthreads();

        bf16x8 av[4], bv[4];
        #pragma unroll
        for (int mf = 0; mf < 4; ++mf) {
            int row = wm + mf * 16 + lr;
            av[mf] = *(const bf16x8*)(smA + row * 64 + ((lg ^ (row & 3)) << 4));
        }
        #pragma unroll
        for (int nf = 0; nf < 4; ++nf) {
            int row = wn + nf * 16 + lr;
            bv[nf] = *(const bf16x8*)(smB + row * 64 + ((lg ^ (row & 3)) << 4));
        }
        #pragma unroll
        for (int mf = 0; mf < 4; ++mf)
            #pragma unroll
            for (int nf = 0; nf < 4; ++nf)
                acc[mf][nf] = __builtin_amdgcn_mfma_f32_16x16x32_bf16(av[mf], bv[nf], acc[mf][nf], 0, 0, 0);
    }

    // epilogue: C/D layout col=lane&15, row=(lane>>4)*4+j   [verified mapping]
    #pragma unroll
    for (int mf = 0; mf < 4; ++mf) {
        #pragma unroll
        for (int nf = 0; nf < 4; ++nf) {
            #pragma unroll
            for (int j = 0; j < 4; ++j) {
                int row = m0 + wm + mf * 16 + (lg << 2) + j;
                int col = n0 + wn + nf * 16 + lr;
                float v = acc[mf][nf][j];
                if (HAS_BIAS) v += bias[col];
                if (OUT_BF16)
                    ((__hip_bfloat16*)Cout)[(size_t)row * Nn + col] = __float2bfloat16(v);
                else
                    ((float*)Cout)[(size_t)row * Nn + col] = v;
            }
        }
    }
}

// ---------------- adaptive avg-pool 56x56 -> 4x4 on fused qk buffer ----------------
// qk: [B*NPOS][768] bf16 ; agent_qk: [B][16][768] fp32. 4 channels per thread.
__global__ __launch_bounds__(256) void pool_kernel(const __hip_bfloat16* __restrict__ qk,
                                                   float* __restrict__ agent_qk) {
    int idx = blockIdx.x * 256 + threadIdx.x;   // 0 .. 98303
    int ch4 = (idx % 192) * 4;
    int a   = (idx / 192) & 15;
    int b   = idx / 3072;
    int py = a >> 2, px = a & 3;
    const __hip_bfloat16* base = qk + (size_t)b * NPOS * CQK + ch4;
    float s0 = 0.f, s1 = 0.f, s2 = 0.f, s3 = 0.f;
    for (int dy = 0; dy < 14; ++dy) {
        int rowbase = (py * 14 + dy) * 56 + px * 14;
        #pragma unroll
        for (int dx = 0; dx < 14; ++dx) {
            union { uint2 u; __hip_bfloat16 h[4]; } v;
            v.u = *(const uint2*)(base + (size_t)(rowbase + dx) * CQK);
            s0 += (float)v.h[0];
            s1 += (float)v.h[1];
            s2 += (float)v.h[2];
            s3 += (float)v.h[3];
        }
    }
    float4 o;
    o.x = s0 * kInv196; o.y = s1 * kInv196; o.z = s2 * kInv196; o.w = s3 * kInv196;
    ((float4*)agent_qk)[idx] = o;
}

// ---------------- agent gating + agent_new (per-batch block, fp32) ----------------
__global__ __launch_bounds__(256) void agent_kernel(
    const float* __restrict__ agqk,    // [B][16][768]
    const float* __restrict__ w_g,     // [384]
    const float* __restrict__ Wp,      // [384][384]
    const float* __restrict__ bp,      // [384]
    __hip_bfloat16* __restrict__ anb,  // [B][16][384] agent_new bf16
    __hip_bfloat16* __restrict__ akb)  // [B][16][384] agent_k  bf16
{
    __shared__ float aq[NAG][NC + 4];
    __shared__ float gk[NAG][NC + 4];
    __shared__ float Av[NAG];
    __shared__ float G[NC];
    const int b = blockIdx.x, t = threadIdx.x;
    const float* base = agqk + (size_t)b * NAG * CQK;

    for (int i = t; i < NAG * NC; i += 256) {
        int a = i / NC, cc = i - a * NC;
        aq[a][cc] = base[a * CQK + cc];
        float kv  = base[a * CQK + NC + cc];
        gk[a][cc] = kv;
        akb[(size_t)b * NAG * NC + i] = __float2bfloat16(kv);
    }
    __syncthreads();

    {   // A[a] = scale * dot(aq[a], w_g)  — 16 threads per agent
        int a = t >> 4, l = t & 15;
        float s = 0.f;
        for (int cc = l; cc < NC; cc += 16) s += aq[a][cc] * w_g[cc];
        s += __shfl_down(s, 8, 16);
        s += __shfl_down(s, 4, 16);
        s += __shfl_down(s, 2, 16);
        s += __shfl_down(s, 1, 16);
        if (l == 0) Av[a] = s * kScale;
    }
    __syncthreads();

    for (int cc = t; cc < NC; cc += 256) {   // G[c] = sum_a A[a]*aq[a][c]
        float s = 0.f;
        #pragma unroll
        for (int a = 0; a < NAG; ++a) s += Av[a] * aq[a][cc];
        G[cc] = s;
    }
    __syncthreads();

    for (int i = t; i < NAG * NC; i += 256) {   // gk = G ∘ agent_k
        int a = i / NC, cc = i - a * NC;
        gk[a][cc] *= G[cc];
    }
    __syncthreads();

    for (int i = t; i < NAG * NC; i += 256) {   // an[a][j] = dot(gk[a], Wp[j]) + bp[j] + aq[a][j]
        int a = i & 15, j = i >> 4;
        float s = 0.f;
        for (int cc = 0; cc < NC; ++cc) s += gk[a][cc] * Wp[(size_t)j * NC + cc];
        anb[(size_t)b * NAG * NC + a * NC + j] = __float2bfloat16(s + bp[j] + aq[a][j]);
    }
}

// ---------------- attention: softmax(q*scale @ an^T) @ ak, per (b,head) ----------------
__global__ __launch_bounds__(256) void attn_kernel(
    const __hip_bfloat16* __restrict__ qk,    // [B*NPOS][768], q = ch 0..383
    const __hip_bfloat16* __restrict__ anb,   // [B][16][384]
    const __hip_bfloat16* __restrict__ akb,   // [B][16][384]
    __hip_bfloat16* __restrict__ outb)        // [B*NPOS][384]
{
    const int bh = blockIdx.x;
    const int b = bh >> 3, hd = bh & 7;
    __shared__ float an_s[NAG][DH];
    __shared__ float ak_s[NAG][DH];
    const int t = threadIdx.x;
    for (int i = t; i < NAG * DH; i += 256) {
        int a = i / DH, dd = i - a * DH;
        an_s[a][dd] = (float)anb[((size_t)b * NAG + a) * NC + hd * DH + dd];
        ak_s[a][dd] = (float)akb[((size_t)b * NAG + a) * NC + hd * DH + dd];
    }
    __syncthreads();
    const int row = blockIdx.y * 256 + t;
    if (row >= NPOS) return;

    union { uint4 u[6]; __hip_bfloat16 h[48]; } qv;
    const uint4* qp = (const uint4*)(qk + ((size_t)b * NPOS + row) * CQK + hd * DH);
    #pragma unroll
    for (int i = 0; i < 6; ++i) qv.u[i] = qp[i];
    float qf[DH];
    #pragma unroll
    for (int dd = 0; dd < DH; ++dd) qf[dd] = (float)qv.h[dd];

    float sv[NAG];
    float mx = -1e30f;
    #pragma unroll
    for (int a = 0; a < NAG; ++a) {
        float s = 0.f;
        #pragma unroll
        for (int dd = 0; dd < DH; ++dd) s += qf[dd] * an_s[a][dd];
        s *= kScale;
        sv[a] = s;
        mx = fmaxf(mx, s);
    }
    float den = 0.f;
    #pragma unroll
    for (int a = 0; a < NAG; ++a) { sv[a] = __expf(sv[a] - mx); den += sv[a]; }
    const float inv = 1.f / den;

    float o[DH];
    #pragma unroll
    for (int dd = 0; dd < DH; ++dd) o[dd] = 0.f;
    #pragma unroll
    for (int a = 0; a < NAG; ++a) {
        float p = sv[a] * inv;
        #pragma unroll
        for (int dd = 0; dd < DH; ++dd) o[dd] += p * ak_s[a][dd];
    }

    union { uint4 u[6]; __hip_bfloat16 h[48]; } ov;
    #pragma unroll
    for (int dd = 0; dd < DH; ++dd) ov.h[dd] = __float2bfloat16(o[dd]);
    uint4* op = (uint4*)(outb + ((size_t)b * NPOS + row) * NC + hd * DH);
    #pragma unroll
    for (int i = 0; i < 6; ++i) op[i] = ov.u[i];
}

// ---------------- launch ----------------
extern "C" void kernel_launch(void* const* d_in, const int* in_sizes, int n_in,
                              void* d_out, int out_size, void* d_ws, size_t ws_size,
                              hipStream_t stream) {
    (void)in_sizes; (void)n_in; (void)out_size; (void)ws_size;
    const float* x   = (const float*)d_in[0];
    const float* Wq  = (const float*)d_in[3];
    const float* Wkv = (const float*)d_in[4];
    const float* wg  = (const float*)d_in[5];
    const float* Wp  = (const float*)d_in[6];
    const float* bp  = (const float*)d_in[7];
    float* out = (float*)d_out;

    // workspace layout (bytes)
    char* w = (char*)d_ws;
    __hip_bfloat16* xb   = (__hip_bfloat16*)(w);                // 77,070,336  x_bf16; later reused as attn_out
    __hip_bfloat16* qkb  = (__hip_bfloat16*)(w + 77070336);     // 154,140,672 fused q|k
    __hip_bfloat16* wqkb = (__hip_bfloat16*)(w + 231211008);    // 589,824     [Wq;Wkv] bf16
    __hip_bfloat16* wpb  = (__hip_bfloat16*)(w + 231800832);    // 294,912     Wp bf16
    float*          agqk = (float*)(w + 232095744);             // 1,572,864   pooled q|k fp32
    __hip_bfloat16* anb  = (__hip_bfloat16*)(w + 233668608);    // 393,216     agent_new bf16
    __hip_bfloat16* akb  = (__hip_bfloat16*)(w + 234061824);    // 393,216     agent_k bf16

    // 1. convert inputs to bf16
    cvt4_kernel<<<37632, 256, 0, stream>>>(x, xb, 9633792);
    cvt4_kernel<<<144, 256, 0, stream>>>(Wq,  wqkb,          36864);
    cvt4_kernel<<<144, 256, 0, stream>>>(Wkv, wqkb + 147456, 36864);
    cvt4_kernel<<<144, 256, 0, stream>>>(Wp,  wpb,           36864);

    // 2. fused q|k GEMM: [100352 x 384] @ [768 x 384]^T -> bf16 [100352 x 768]
    gemm_kernel<false, true><<<dim3(MROWS / 128, CQK / 128), 256, 0, stream>>>(
        xb, wqkb, nullptr, qkb, MROWS, CQK, NC);

    // 3. agent pooling (fp32 accum)
    pool_kernel<<<384, 256, 0, stream>>>(qkb, agqk);

    // 4. agent gating + agent_new (fp32)
    agent_kernel<<<NB, 256, 0, stream>>>(agqk, wg, Wp, bp, anb, akb);

    // 5. attention -> bf16 out (reuses xb region; x no longer needed)
    attn_kernel<<<dim3(NB * NHD, (NPOS + 255) / 256), 256, 0, stream>>>(qkb, anb, akb, xb);

    // 6. final projection GEMM + bias -> fp32 d_out
    gemm_kernel<true, false><<<dim3(MROWS / 128, NC / 128), 256, 0, stream>>>(
        xb, wpb, bp, out, MROWS, NC, NC);
}

// Round 2
// 545.464 us; speedup vs baseline: 1.2239x; 1.2239x over previous
//
#include <hip/hip_runtime.h>
#include <hip/hip_bf16.h>
#include <cstdint>
#include <cstddef>

// Problem constants (fixed by setup_inputs)
#define NB   32
#define NPOS 3136      // 56*56
#define NC   384
#define NHD  8
#define DH   48
#define NAG  16
#define MROWS (NB*NPOS)   // 100352
#define CQK  768

static constexpr float kScale = 0.14433756729740643f;   // 48^-0.5
static constexpr float kInv196 = 1.0f / 196.0f;

typedef __bf16 bf16x8 __attribute__((ext_vector_type(8)));
typedef float  f32x4  __attribute__((ext_vector_type(4)));

// ---------------- fp32 -> bf16 convert (x4 vectorized) ----------------
__global__ __launch_bounds__(256) void cvt4_kernel(const float* __restrict__ src,
                                                   __hip_bfloat16* __restrict__ dst,
                                                   int n4) {
    int i = blockIdx.x * 256 + threadIdx.x;
    if (i >= n4) return;
    float4 v = ((const float4*)src)[i];
    union { ushort4 u; __hip_bfloat16 h[4]; } p;
    p.h[0] = __float2bfloat16(v.x);
    p.h[1] = __float2bfloat16(v.y);
    p.h[2] = __float2bfloat16(v.z);
    p.h[3] = __float2bfloat16(v.w);
    ((ushort4*)dst)[i] = p.u;
}

// ---------------- bf16 MFMA GEMM: C[M][Nn] = A[M][K] * B[Nn][K]^T (+bias, +resid) ----------------
// 128x128 tile, BK=32, 256 threads (4 waves, 2x2 of 64x64), chunk-XOR LDS swizzle.
template<bool HAS_BIAS, bool OUT_BF16, bool RESID>
__global__ __launch_bounds__(256) void gemm_kernel(
    const __hip_bfloat16* __restrict__ A,
    const __hip_bfloat16* __restrict__ Bw,
    const float* __restrict__ bias,
    const float* __restrict__ resid,
    void* __restrict__ Cout,
    int M, int Nn, int K)
{
    __shared__ unsigned char smem[16384];
    unsigned char* smA = smem;
    unsigned char* smB = smem + 8192;

    const int t    = threadIdx.x;
    const int m0   = blockIdx.x * 128;
    const int n0   = blockIdx.y * 128;
    const int lane = t & 63;
    const int wv   = t >> 6;
    const int wm   = (wv >> 1) * 64;
    const int wn   = (wv & 1) * 64;
    const int lr   = lane & 15;
    const int lg   = lane >> 4;

    // staging decomposition: 512 16B-chunks per tile, 2 per thread
    const int r0 = t >> 2;      // row 0..63
    const int c0 = t & 3;       // 16B chunk within 64B row
    const int sc = (c0 ^ (r0 & 3)) << 4;   // swizzled chunk byte offset

    f32x4 acc[4][4] = {};

    const int nk = K >> 5;
    for (int kt = 0; kt < nk; ++kt) {
        const int k0 = kt << 5;
        // global loads (issued before barrier to overlap latency)
        uint4 a0 = *(const uint4*)(A  + (size_t)(m0 + r0)      * K + k0 + c0 * 8);
        uint4 a1 = *(const uint4*)(A  + (size_t)(m0 + r0 + 64) * K + k0 + c0 * 8);
        uint4 b0 = *(const uint4*)(Bw + (size_t)(n0 + r0)      * K + k0 + c0 * 8);
        uint4 b1 = *(const uint4*)(Bw + (size_t)(n0 + r0 + 64) * K + k0 + c0 * 8);
        __syncthreads();   // previous tile fully consumed
        *(uint4*)(smA + r0 * 64        + sc) = a0;
        *(uint4*)(smA + (r0 + 64) * 64 + sc) = a1;   // (r0+64)&3 == r0&3
        *(uint4*)(smB + r0 * 64        + sc) = b0;
        *(uint4*)(smB + (r0 + 64) * 64 + sc) = b1;
        __syncthreads();

        bf16x8 av[4], bv[4];
        #pragma unroll
        for (int mf = 0; mf < 4; ++mf) {
            int row = wm + mf * 16 + lr;
            av[mf] = *(const bf16x8*)(smA + row * 64 + ((lg ^ (row & 3)) << 4));
        }
        #pragma unroll
        for (int nf = 0; nf < 4; ++nf) {
            int row = wn + nf * 16 + lr;
            bv[nf] = *(const bf16x8*)(smB + row * 64 + ((lg ^ (row & 3)) << 4));
        }
        #pragma unroll
        for (int mf = 0; mf < 4; ++mf)
            #pragma unroll
            for (int nf = 0; nf < 4; ++nf)
                acc[mf][nf] = __builtin_amdgcn_mfma_f32_16x16x32_bf16(av[mf], bv[nf], acc[mf][nf], 0, 0, 0);
    }

    // epilogue: C/D layout col=lane&15, row=(lane>>4)*4+j   [verified mapping]
    #pragma unroll
    for (int mf = 0; mf < 4; ++mf) {
        #pragma unroll
        for (int nf = 0; nf < 4; ++nf) {
            #pragma unroll
            for (int j = 0; j < 4; ++j) {
                int row = m0 + wm + mf * 16 + (lg << 2) + j;
                int col = n0 + wn + nf * 16 + lr;
                float v = acc[mf][nf][j];
                if (HAS_BIAS) v += bias[col];
                if (RESID)    v += resid[(size_t)row * Nn + col];
                if (OUT_BF16)
                    ((__hip_bfloat16*)Cout)[(size_t)row * Nn + col] = __float2bfloat16(v);
                else
                    ((float*)Cout)[(size_t)row * Nn + col] = v;
            }
        }
    }
}

// ---------------- adaptive avg-pool 56x56 -> 4x4 on fused qk buffer ----------------
// qk: [B*NPOS][768] bf16 ; agent_qk: [B][16][768] fp32. 4 channels per thread.
__global__ __launch_bounds__(256) void pool_kernel(const __hip_bfloat16* __restrict__ qk,
                                                   float* __restrict__ agent_qk) {
    int idx = blockIdx.x * 256 + threadIdx.x;   // 0 .. 98303
    int ch4 = (idx % 192) * 4;
    int a   = (idx / 192) & 15;
    int b   = idx / 3072;
    int py = a >> 2, px = a & 3;
    const __hip_bfloat16* base = qk + (size_t)b * NPOS * CQK + ch4;
    float s0 = 0.f, s1 = 0.f, s2 = 0.f, s3 = 0.f;
    for (int dy = 0; dy < 14; ++dy) {
        int rowbase = (py * 14 + dy) * 56 + px * 14;
        #pragma unroll
        for (int dx = 0; dx < 14; ++dx) {
            union { uint2 u; __hip_bfloat16 h[4]; } v;
            v.u = *(const uint2*)(base + (size_t)(rowbase + dx) * CQK);
            s0 += (float)v.h[0];
            s1 += (float)v.h[1];
            s2 += (float)v.h[2];
            s3 += (float)v.h[3];
        }
    }
    float4 o;
    o.x = s0 * kInv196; o.y = s1 * kInv196; o.z = s2 * kInv196; o.w = s3 * kInv196;
    ((float4*)agent_qk)[idx] = o;
}

// ---------------- agent gating prep (per-batch block, fp32) ----------------
// Emits: gkb = bf16(G ∘ agent_k), akb = bf16(agent_k), aqf = fp32 agent_q (residual)
__global__ __launch_bounds__(256) void agent_prep_kernel(
    const float* __restrict__ agqk,    // [B][16][768]
    const float* __restrict__ w_g,     // [384]
    __hip_bfloat16* __restrict__ gkb,  // [B*16][384]
    __hip_bfloat16* __restrict__ akb,  // [B*16][384]
    float* __restrict__ aqf)           // [B*16][384]
{
    __shared__ float aq[NAG][NC];
    __shared__ float Av[NAG];
    __shared__ float G[NC];
    const int b = blockIdx.x, t = threadIdx.x;
    const float* base = agqk + (size_t)b * NAG * CQK;

    for (int i = t; i < NAG * NC; i += 256) {
        int a = i / NC, cc = i - a * NC;
        aq[a][cc] = base[a * CQK + cc];
    }
    __syncthreads();

    {   // A[a] = scale * dot(aq[a], w_g)  — 16 threads per agent
        int a = t >> 4, l = t & 15;
        float s = 0.f;
        for (int cc = l; cc < NC; cc += 16) s += aq[a][cc] * w_g[cc];
        s += __shfl_down(s, 8, 16);
        s += __shfl_down(s, 4, 16);
        s += __shfl_down(s, 2, 16);
        s += __shfl_down(s, 1, 16);
        if (l == 0) Av[a] = s * kScale;
    }
    __syncthreads();

    for (int cc = t; cc < NC; cc += 256) {   // G[c] = sum_a A[a]*aq[a][c]
        float s = 0.f;
        #pragma unroll
        for (int a = 0; a < NAG; ++a) s += Av[a] * aq[a][cc];
        G[cc] = s;
    }
    __syncthreads();

    for (int i = t; i < NAG * NC; i += 256) {
        int a = i / NC, cc = i - a * NC;
        float kv = base[a * CQK + NC + cc];
        size_t o = (size_t)b * NAG * NC + i;
        akb[o] = __float2bfloat16(kv);
        gkb[o] = __float2bfloat16(G[cc] * kv);
        aqf[o] = aq[a][cc];
    }
}

// ---------------- attention: softmax(q*scale @ an^T) @ ak, per (b,head) ----------------
__global__ __launch_bounds__(256) void attn_kernel(
    const __hip_bfloat16* __restrict__ qk,    // [B*NPOS][768], q = ch 0..383
    const __hip_bfloat16* __restrict__ anb,   // [B][16][384]
    const __hip_bfloat16* __restrict__ akb,   // [B][16][384]
    __hip_bfloat16* __restrict__ outb)        // [B*NPOS][384]
{
    const int bh = blockIdx.x;
    const int b = bh >> 3, hd = bh & 7;
    __shared__ float an_s[NAG][DH];
    __shared__ float ak_s[NAG][DH];
    const int t = threadIdx.x;
    for (int i = t; i < NAG * DH; i += 256) {
        int a = i / DH, dd = i - a * DH;
        an_s[a][dd] = (float)anb[((size_t)b * NAG + a) * NC + hd * DH + dd];
        ak_s[a][dd] = (float)akb[((size_t)b * NAG + a) * NC + hd * DH + dd];
    }
    __syncthreads();
    const int row = blockIdx.y * 256 + t;
    if (row >= NPOS) return;

    union { uint4 u[6]; __hip_bfloat16 h[48]; } qv;
    const uint4* qp = (const uint4*)(qk + ((size_t)b * NPOS + row) * CQK + hd * DH);
    #pragma unroll
    for (int i = 0; i < 6; ++i) qv.u[i] = qp[i];
    float qf[DH];
    #pragma unroll
    for (int dd = 0; dd < DH; ++dd) qf[dd] = (float)qv.h[dd];

    float sv[NAG];
    float mx = -1e30f;
    #pragma unroll
    for (int a = 0; a < NAG; ++a) {
        float s = 0.f;
        #pragma unroll
        for (int dd = 0; dd < DH; ++dd) s += qf[dd] * an_s[a][dd];
        s *= kScale;
        sv[a] = s;
        mx = fmaxf(mx, s);
    }
    float den = 0.f;
    #pragma unroll
    for (int a = 0; a < NAG; ++a) { sv[a] = __expf(sv[a] - mx); den += sv[a]; }
    const float inv = 1.f / den;

    float o[DH];
    #pragma unroll
    for (int dd = 0; dd < DH; ++dd) o[dd] = 0.f;
    #pragma unroll
    for (int a = 0; a < NAG; ++a) {
        float p = sv[a] * inv;
        #pragma unroll
        for (int dd = 0; dd < DH; ++dd) o[dd] += p * ak_s[a][dd];
    }

    union { uint4 u[6]; __hip_bfloat16 h[48]; } ov;
    #pragma unroll
    for (int dd = 0; dd < DH; ++dd) ov.h[dd] = __float2bfloat16(o[dd]);
    uint4* op = (uint4*)(outb + ((size_t)b * NPOS + row) * NC + hd * DH);
    #pragma unroll
    for (int i = 0; i < 6; ++i) op[i] = ov.u[i];
}

// ---------------- launch ----------------
extern "C" void kernel_launch(void* const* d_in, const int* in_sizes, int n_in,
                              void* d_out, int out_size, void* d_ws, size_t ws_size,
                              hipStream_t stream) {
    (void)in_sizes; (void)n_in; (void)out_size; (void)ws_size;
    const float* x   = (const float*)d_in[0];
    const float* Wq  = (const float*)d_in[3];
    const float* Wkv = (const float*)d_in[4];
    const float* wg  = (const float*)d_in[5];
    const float* Wp  = (const float*)d_in[6];
    const float* bp  = (const float*)d_in[7];
    float* out = (float*)d_out;

    // workspace layout (bytes)
    char* w = (char*)d_ws;
    __hip_bfloat16* xb   = (__hip_bfloat16*)(w);                // 77,070,336  x_bf16; later reused as attn_out
    __hip_bfloat16* qkb  = (__hip_bfloat16*)(w + 77070336);     // 154,140,672 fused q|k
    __hip_bfloat16* wqkb = (__hip_bfloat16*)(w + 231211008);    // 589,824     [Wq;Wkv] bf16
    __hip_bfloat16* wpb  = (__hip_bfloat16*)(w + 231800832);    // 294,912     Wp bf16
    float*          agqk = (float*)(w + 232095744);             // 1,572,864   pooled q|k fp32
    __hip_bfloat16* anb  = (__hip_bfloat16*)(w + 233668608);    // 393,216     agent_new bf16
    __hip_bfloat16* akb  = (__hip_bfloat16*)(w + 234061824);    // 393,216     agent_k bf16

    // gkb/aqf overlay the head of xb: x_bf16 is dead after GEMM-1 (its only
    // reader), and attn (which overwrites xb) runs only after the agent GEMM
    // has consumed gkb/aqf — stream order makes this safe.
    __hip_bfloat16* gkb = (__hip_bfloat16*)(w);                 // 393,216   G∘agent_k bf16
    float*          aqf = (float*)(w + 393216);                 // 786,432   agent_q fp32 (residual)

    // 1. convert inputs to bf16
    cvt4_kernel<<<37632, 256, 0, stream>>>(x, xb, 9633792);
    cvt4_kernel<<<144, 256, 0, stream>>>(Wq,  wqkb,          36864);
    cvt4_kernel<<<144, 256, 0, stream>>>(Wkv, wqkb + 147456, 36864);
    cvt4_kernel<<<144, 256, 0, stream>>>(Wp,  wpb,           36864);

    // 2. fused q|k GEMM: [100352 x 384] @ [768 x 384]^T -> bf16 [100352 x 768]
    gemm_kernel<false, true, false><<<dim3(MROWS / 128, CQK / 128), 256, 0, stream>>>(
        xb, wqkb, nullptr, nullptr, qkb, MROWS, CQK, NC);

    // 3. agent pooling (fp32 accum)
    pool_kernel<<<384, 256, 0, stream>>>(qkb, agqk);

    // 4. agent gating prep (A, G, gk, ak)
    agent_prep_kernel<<<NB, 256, 0, stream>>>(agqk, wg, gkb, akb, aqf);

    // 5. agent_new GEMM: [512 x 384] = gk @ Wp^T + bp + aq   (MFMA, grid 4x3)
    gemm_kernel<true, true, true><<<dim3(4, 3), 256, 0, stream>>>(
        gkb, wpb, bp, aqf, anb, NB * NAG, NC, NC);

    // 6. attention -> bf16 out (reuses xb region; x no longer needed)
    attn_kernel<<<dim3(NB * NHD, (NPOS + 255) / 256), 256, 0, stream>>>(qkb, anb, akb, xb);

    // 7. final projection GEMM + bias -> fp32 d_out
    gemm_kernel<true, false, false><<<dim3(MROWS / 128, NC / 128), 256, 0, stream>>>(
        xb, wpb, bp, nullptr, out, MROWS, NC, NC);
}

// Round 3
// 532.994 us; speedup vs baseline: 1.2525x; 1.0234x over previous
//
#include <hip/hip_runtime.h>
#include <hip/hip_bf16.h>
#include <cstdint>
#include <cstddef>

// Problem constants (fixed by setup_inputs)
#define NB   32
#define NPOS 3136      // 56*56
#define NC   384
#define NHD  8
#define DH   48
#define NAG  16
#define MROWS (NB*NPOS)   // 100352
#define CQK  768

static constexpr float kScale = 0.14433756729740643f;   // 48^-0.5
static constexpr float kInv196 = 1.0f / 196.0f;

typedef __bf16 bf16x8 __attribute__((ext_vector_type(8)));
typedef float  f32x4  __attribute__((ext_vector_type(4)));

// async global->LDS, 16B per lane (wave-uniform LDS base + lane*16 dest)
__device__ static inline void async_copy16(void* lds, const void* g) {
    __builtin_amdgcn_global_load_lds(
        (const __attribute__((address_space(1))) unsigned int*)g,
        (__attribute__((address_space(3))) unsigned int*)lds, 16, 0, 0);
}

// ---------------- fp32 -> bf16 convert (x4 vectorized) ----------------
__global__ __launch_bounds__(256) void cvt4_kernel(const float* __restrict__ src,
                                                   __hip_bfloat16* __restrict__ dst,
                                                   int n4) {
    int i = blockIdx.x * 256 + threadIdx.x;
    if (i >= n4) return;
    float4 v = ((const float4*)src)[i];
    union { ushort4 u; __hip_bfloat16 h[4]; } p;
    p.h[0] = __float2bfloat16(v.x);
    p.h[1] = __float2bfloat16(v.y);
    p.h[2] = __float2bfloat16(v.z);
    p.h[3] = __float2bfloat16(v.w);
    ((ushort4*)dst)[i] = p.u;
}

// ---------------- bf16 MFMA GEMM: C[M][Nn] = A[M][K] * B[Nn][K]^T (+bias, +resid) --------------
// 128x128 tile, BK=64, 256 threads (4 waves, 2x2 of 64x64).
// global_load_lds staging: linear LDS dest, XOR-involution slot^(row&7) applied to the
// per-lane GLOBAL source and again on the ds_read side (rule: both-sides-or-neither).
// 1-D grid, n-tile fastest (bid % nBlkN) so blocks sharing an A-panel are co-resident (L3 reuse).
template<bool HAS_BIAS, bool OUT_BF16, bool RESID>
__global__ __launch_bounds__(256) void gemm_kernel(
    const __hip_bfloat16* __restrict__ A,
    const __hip_bfloat16* __restrict__ Bw,
    const float* __restrict__ bias,
    const float* __restrict__ resid,
    void* __restrict__ Cout,
    int nBlkN, int Nn, int K)
{
    __shared__ unsigned char smem[32768];
    unsigned char* smA = smem;            // [128 rows][128 B]
    unsigned char* smB = smem + 16384;

    const int t    = threadIdx.x;
    const int m0   = (blockIdx.x / nBlkN) * 128;
    const int n0   = (blockIdx.x % nBlkN) * 128;
    const int lane = t & 63;
    const int w    = t >> 6;
    const int wm   = (w >> 1) * 64;
    const int wn   = (w & 1) * 64;
    const int lr   = lane & 15;
    const int lg   = lane >> 4;

    // staging: wave w covers rows 32w..32w+31 in 4 instructions of 8 rows (1 KiB) each.
    // lane l -> row (l>>3), physical slot (l&7); source slot = (l&7) ^ (l>>3)  (row&7 == l>>3).
    const int Kb    = K << 1;                       // row bytes
    const int lrow  = lane >> 3;                    // 0..7
    const int lslot = ((lane & 7) ^ lrow) << 4;     // swizzled source byte-in-128B
    const char* Ag = (const char*)A  + (size_t)(m0 + 32 * w + lrow) * Kb + lslot;
    const char* Bg = (const char*)Bw + (size_t)(n0 + 32 * w + lrow) * Kb + lslot;
    unsigned char* ldsA = smA + w * 4096;
    unsigned char* ldsB = smB + w * 4096;

    f32x4 acc[4][4] = {};

    const int nk = K >> 6;
    for (int kt = 0; kt < nk; ++kt) {
        __syncthreads();    // previous tile fully consumed
        #pragma unroll
        for (int j = 0; j < 4; ++j) {
            async_copy16(ldsA + j * 1024, Ag + (size_t)(8 * j) * Kb);
            async_copy16(ldsB + j * 1024, Bg + (size_t)(8 * j) * Kb);
        }
        Ag += 128; Bg += 128;
        __syncthreads();    // compiler drains vmcnt(0) before barrier -> tile ready

        #pragma unroll
        for (int kk = 0; kk < 2; ++kk) {
            bf16x8 av[4], bv[4];
            #pragma unroll
            for (int mf = 0; mf < 4; ++mf) {
                const int row = wm + mf * 16 + lr;
                av[mf] = *(const bf16x8*)(smA + row * 128 + ((((kk << 2) | lg) ^ (row & 7)) << 4));
            }
            #pragma unroll
            for (int nf = 0; nf < 4; ++nf) {
                const int row = wn + nf * 16 + lr;
                bv[nf] = *(const bf16x8*)(smB + row * 128 + ((((kk << 2) | lg) ^ (row & 7)) << 4));
            }
            #pragma unroll
            for (int mf = 0; mf < 4; ++mf)
                #pragma unroll
                for (int nf = 0; nf < 4; ++nf)
                    acc[mf][nf] = __builtin_amdgcn_mfma_f32_16x16x32_bf16(av[mf], bv[nf], acc[mf][nf], 0, 0, 0);
        }
    }

    // epilogue: C/D layout col=lane&15, row=(lane>>4)*4+j   [verified mapping]
    #pragma unroll
    for (int mf = 0; mf < 4; ++mf) {
        #pragma unroll
        for (int nf = 0; nf < 4; ++nf) {
            #pragma unroll
            for (int j = 0; j < 4; ++j) {
                int row = m0 + wm + mf * 16 + (lg << 2) + j;
                int col = n0 + wn + nf * 16 + lr;
                float v = acc[mf][nf][j];
                if (HAS_BIAS) v += bias[col];
                if (RESID)    v += resid[(size_t)row * Nn + col];
                if (OUT_BF16)
                    ((__hip_bfloat16*)Cout)[(size_t)row * Nn + col] = __float2bfloat16(v);
                else
                    ((float*)Cout)[(size_t)row * Nn + col] = v;
            }
        }
    }
}

// ---------------- adaptive avg-pool 56x56 -> 4x4 on fused qk buffer ----------------
// qk: [B*NPOS][768] bf16 ; agent_qk: [B][16][768] fp32. 4 channels per thread.
__global__ __launch_bounds__(256) void pool_kernel(const __hip_bfloat16* __restrict__ qk,
                                                   float* __restrict__ agent_qk) {
    int idx = blockIdx.x * 256 + threadIdx.x;   // 0 .. 98303
    int ch4 = (idx % 192) * 4;
    int a   = (idx / 192) & 15;
    int b   = idx / 3072;
    int py = a >> 2, px = a & 3;
    const __hip_bfloat16* base = qk + (size_t)b * NPOS * CQK + ch4;
    float s0 = 0.f, s1 = 0.f, s2 = 0.f, s3 = 0.f;
    for (int dy = 0; dy < 14; ++dy) {
        int rowbase = (py * 14 + dy) * 56 + px * 14;
        #pragma unroll
        for (int dx = 0; dx < 14; ++dx) {
            union { uint2 u; __hip_bfloat16 h[4]; } v;
            v.u = *(const uint2*)(base + (size_t)(rowbase + dx) * CQK);
            s0 += (float)v.h[0];
            s1 += (float)v.h[1];
            s2 += (float)v.h[2];
            s3 += (float)v.h[3];
        }
    }
    float4 o;
    o.x = s0 * kInv196; o.y = s1 * kInv196; o.z = s2 * kInv196; o.w = s3 * kInv196;
    ((float4*)agent_qk)[idx] = o;
}

// ---------------- agent gating prep (per-batch block, fp32) ----------------
// Emits: gkb = bf16(G ∘ agent_k), akb = bf16(agent_k), aqf = fp32 agent_q (residual)
__global__ __launch_bounds__(256) void agent_prep_kernel(
    const float* __restrict__ agqk,    // [B][16][768]
    const float* __restrict__ w_g,     // [384]
    __hip_bfloat16* __restrict__ gkb,  // [B*16][384]
    __hip_bfloat16* __restrict__ akb,  // [B*16][384]
    float* __restrict__ aqf)           // [B*16][384]
{
    __shared__ float aq[NAG][NC];
    __shared__ float Av[NAG];
    __shared__ float G[NC];
    const int b = blockIdx.x, t = threadIdx.x;
    const float* base = agqk + (size_t)b * NAG * CQK;

    for (int i = t; i < NAG * NC; i += 256) {
        int a = i / NC, cc = i - a * NC;
        aq[a][cc] = base[a * CQK + cc];
    }
    __syncthreads();

    {   // A[a] = scale * dot(aq[a], w_g)  — 16 threads per agent
        int a = t >> 4, l = t & 15;
        float s = 0.f;
        for (int cc = l; cc < NC; cc += 16) s += aq[a][cc] * w_g[cc];
        s += __shfl_down(s, 8, 16);
        s += __shfl_down(s, 4, 16);
        s += __shfl_down(s, 2, 16);
        s += __shfl_down(s, 1, 16);
        if (l == 0) Av[a] = s * kScale;
    }
    __syncthreads();

    for (int cc = t; cc < NC; cc += 256) {   // G[c] = sum_a A[a]*aq[a][c]
        float s = 0.f;
        #pragma unroll
        for (int a = 0; a < NAG; ++a) s += Av[a] * aq[a][cc];
        G[cc] = s;
    }
    __syncthreads();

    for (int i = t; i < NAG * NC; i += 256) {
        int a = i / NC, cc = i - a * NC;
        float kv = base[a * CQK + NC + cc];
        size_t o = (size_t)b * NAG * NC + i;
        akb[o] = __float2bfloat16(kv);
        gkb[o] = __float2bfloat16(G[cc] * kv);
        aqf[o] = aq[a][cc];
    }
}

// ---------------- attention: softmax(q*scale @ an^T) @ ak, per (b,head) ----------------
__global__ __launch_bounds__(256) void attn_kernel(
    const __hip_bfloat16* __restrict__ qk,    // [B*NPOS][768], q = ch 0..383
    const __hip_bfloat16* __restrict__ anb,   // [B][16][384]
    const __hip_bfloat16* __restrict__ akb,   // [B][16][384]
    __hip_bfloat16* __restrict__ outb)        // [B*NPOS][384]
{
    const int bh = blockIdx.x;
    const int b = bh >> 3, hd = bh & 7;
    __shared__ float an_s[NAG][DH];
    __shared__ float ak_s[NAG][DH];
    const int t = threadIdx.x;
    for (int i = t; i < NAG * DH; i += 256) {
        int a = i / DH, dd = i - a * DH;
        an_s[a][dd] = (float)anb[((size_t)b * NAG + a) * NC + hd * DH + dd];
        ak_s[a][dd] = (float)akb[((size_t)b * NAG + a) * NC + hd * DH + dd];
    }
    __syncthreads();
    const int row = blockIdx.y * 256 + t;
    if (row >= NPOS) return;

    union { uint4 u[6]; __hip_bfloat16 h[48]; } qv;
    const uint4* qp = (const uint4*)(qk + ((size_t)b * NPOS + row) * CQK + hd * DH);
    #pragma unroll
    for (int i = 0; i < 6; ++i) qv.u[i] = qp[i];
    float qf[DH];
    #pragma unroll
    for (int dd = 0; dd < DH; ++dd) qf[dd] = (float)qv.h[dd];

    float sv[NAG];
    float mx = -1e30f;
    #pragma unroll
    for (int a = 0; a < NAG; ++a) {
        float s = 0.f;
        #pragma unroll
        for (int dd = 0; dd < DH; ++dd) s += qf[dd] * an_s[a][dd];
        s *= kScale;
        sv[a] = s;
        mx = fmaxf(mx, s);
    }
    float den = 0.f;
    #pragma unroll
    for (int a = 0; a < NAG; ++a) { sv[a] = __expf(sv[a] - mx); den += sv[a]; }
    const float inv = 1.f / den;

    float o[DH];
    #pragma unroll
    for (int dd = 0; dd < DH; ++dd) o[dd] = 0.f;
    #pragma unroll
    for (int a = 0; a < NAG; ++a) {
        float p = sv[a] * inv;
        #pragma unroll
        for (int dd = 0; dd < DH; ++dd) o[dd] += p * ak_s[a][dd];
    }

    union { uint4 u[6]; __hip_bfloat16 h[48]; } ov;
    #pragma unroll
    for (int dd = 0; dd < DH; ++dd) ov.h[dd] = __float2bfloat16(o[dd]);
    uint4* op = (uint4*)(outb + ((size_t)b * NPOS + row) * NC + hd * DH);
    #pragma unroll
    for (int i = 0; i < 6; ++i) op[i] = ov.u[i];
}

// ---------------- launch ----------------
extern "C" void kernel_launch(void* const* d_in, const int* in_sizes, int n_in,
                              void* d_out, int out_size, void* d_ws, size_t ws_size,
                              hipStream_t stream) {
    (void)in_sizes; (void)n_in; (void)out_size; (void)ws_size;
    const float* x   = (const float*)d_in[0];
    const float* Wq  = (const float*)d_in[3];
    const float* Wkv = (const float*)d_in[4];
    const float* wg  = (const float*)d_in[5];
    const float* Wp  = (const float*)d_in[6];
    const float* bp  = (const float*)d_in[7];
    float* out = (float*)d_out;

    // workspace layout (bytes)
    char* w = (char*)d_ws;
    __hip_bfloat16* xb   = (__hip_bfloat16*)(w);                // 77,070,336  x_bf16; later reused as attn_out
    __hip_bfloat16* qkb  = (__hip_bfloat16*)(w + 77070336);     // 154,140,672 fused q|k
    __hip_bfloat16* wqkb = (__hip_bfloat16*)(w + 231211008);    // 589,824     [Wq;Wkv] bf16
    __hip_bfloat16* wpb  = (__hip_bfloat16*)(w + 231800832);    // 294,912     Wp bf16
    float*          agqk = (float*)(w + 232095744);             // 1,572,864   pooled q|k fp32
    __hip_bfloat16* anb  = (__hip_bfloat16*)(w + 233668608);    // 393,216     agent_new bf16
    __hip_bfloat16* akb  = (__hip_bfloat16*)(w + 234061824);    // 393,216     agent_k bf16

    // gkb/aqf overlay the head of xb: x_bf16 is dead after GEMM-1 (its only
    // reader), and attn (which overwrites xb) runs only after the agent GEMM
    // has consumed gkb/aqf — stream order makes this safe.
    __hip_bfloat16* gkb = (__hip_bfloat16*)(w);                 // 393,216   G∘agent_k bf16
    float*          aqf = (float*)(w + 393216);                 // 786,432   agent_q fp32 (residual)

    // 1. convert inputs to bf16
    cvt4_kernel<<<37632, 256, 0, stream>>>(x, xb, 9633792);
    cvt4_kernel<<<144, 256, 0, stream>>>(Wq,  wqkb,          36864);
    cvt4_kernel<<<144, 256, 0, stream>>>(Wkv, wqkb + 147456, 36864);
    cvt4_kernel<<<144, 256, 0, stream>>>(Wp,  wpb,           36864);

    // 2. fused q|k GEMM: [100352 x 384] @ [768 x 384]^T -> bf16 [100352 x 768]
    gemm_kernel<false, true, false><<<(MROWS / 128) * (CQK / 128), 256, 0, stream>>>(
        xb, wqkb, nullptr, nullptr, qkb, CQK / 128, CQK, NC);

    // 3. agent pooling (fp32 accum)
    pool_kernel<<<384, 256, 0, stream>>>(qkb, agqk);

    // 4. agent gating prep (A, G, gk, ak)
    agent_prep_kernel<<<NB, 256, 0, stream>>>(agqk, wg, gkb, akb, aqf);

    // 5. agent_new GEMM: [512 x 384] = gk @ Wp^T + bp + aq   (MFMA)
    gemm_kernel<true, true, true><<<4 * 3, 256, 0, stream>>>(
        gkb, wpb, bp, aqf, anb, NC / 128, NC, NC);

    // 6. attention -> bf16 out (reuses xb region; x no longer needed)
    attn_kernel<<<dim3(NB * NHD, (NPOS + 255) / 256), 256, 0, stream>>>(qkb, anb, akb, xb);

    // 7. final projection GEMM + bias -> fp32 d_out
    gemm_kernel<true, false, false><<<(MROWS / 128) * (NC / 128), 256, 0, stream>>>(
        xb, wpb, bp, nullptr, out, NC / 128, NC, NC);
}